// Round 10
// baseline (36.667 us; speedup 1.0000x reference)
//
#include <hip/hip_runtime.h>

#define FH 128
#define FW 128
#define CPLANE 490                 // 10*7*7 input channels; plane c_in serves bin (ph,pw)
#define NBATCH 4
#define NPLANES (NBATCH * CPLANE)  // 1960 = 8 * 245
#define SSCALE 0.0625f
#define GRIDB 512                  // persistent: 2 blocks/CU, all co-resident

typedef float f32x4 __attribute__((ext_vector_type(4)));

// ---- kernel A: bucket roi indices by batch into d_ws -----------------------
// ws layout (proven safe, 8.2 KB): ws[0..3]=counts, ws[4 + b*R + slot]=roi idx
__global__ __launch_bounds__(1024) void bucket_rois(const float* __restrict__ rois,
                                                    int R, int* __restrict__ ws) {
    __shared__ int cnt[NBATCH];
    if (threadIdx.x < NBATCH) cnt[threadIdx.x] = 0;
    __syncthreads();
    for (int i = threadIdx.x; i < R; i += blockDim.x) {
        int b = (int)rois[(size_t)i * 5];
        int slot = atomicAdd(&cnt[b], 1);
        ws[NBATCH + b * R + slot] = i;
    }
    __syncthreads();
    if (threadIdx.x < NBATCH) ws[threadIdx.x] = cnt[threadIdx.x];
}

__device__ __forceinline__ int swz(int g) {          // XCD-chunked bijection
    return (g & 7) * (NPLANES / 8) + (g >> 3);
}

// ---- kernel B: persistent, plane-per-iteration, T14 prefetch ----------------
// Per plane: ds_write(staged regs) -> barrier -> issue NEXT plane's NT loads ->
// gather current from LDS -> barrier. HBM latency drains under the gather.
__global__ __launch_bounds__(1024, 8) void psroi_stream(const float* __restrict__ feat,
                                                        const float* __restrict__ rois,
                                                        const int* __restrict__ ws,
                                                        float* __restrict__ out, int R) {
    __shared__ float plane[FH * FW];   // 64 KB -> 2 blocks/CU, 32 waves/CU
    const int tid = threadIdx.x;
    const int bid = blockIdx.x;

    const int   sub = tid & 3;                       // bilinear sample id
    const float sy  = 0.25f + 0.5f * (float)(sub >> 1);
    const float sx  = 0.25f + 0.5f * (float)(sub & 1);

    // prologue: issue loads for first plane
    int gcur = bid;                                  // < NPLANES always (512 < 1960)
    int plc  = swz(gcur);
    const f32x4* src = (const f32x4*)(feat + (size_t)plc * (FH * FW));
    f32x4 s0 = __builtin_nontemporal_load(src + 0 * 1024 + tid);
    f32x4 s1 = __builtin_nontemporal_load(src + 1 * 1024 + tid);
    f32x4 s2 = __builtin_nontemporal_load(src + 2 * 1024 + tid);
    f32x4 s3 = __builtin_nontemporal_load(src + 3 * 1024 + tid);

    for (;;) {
        // commit staged regs to LDS (compiler inserts the vmcnt wait here)
        *(f32x4*)(plane + (0 * 1024 + tid) * 4) = s0;
        *(f32x4*)(plane + (1 * 1024 + tid) * 4) = s1;
        *(f32x4*)(plane + (2 * 1024 + tid) * 4) = s2;
        *(f32x4*)(plane + (3 * 1024 + tid) * 4) = s3;
        __syncthreads();                             // plane visible to all waves

        // issue next plane's loads NOW; they drain during the gather below
        const int gnext = gcur + GRIDB;
        const bool more = (gnext < NPLANES);
        int pln = 0;
        if (more) {
            pln = swz(gnext);
            const f32x4* srcn = (const f32x4*)(feat + (size_t)pln * (FH * FW));
            s0 = __builtin_nontemporal_load(srcn + 0 * 1024 + tid);
            s1 = __builtin_nontemporal_load(srcn + 1 * 1024 + tid);
            s2 = __builtin_nontemporal_load(srcn + 2 * 1024 + tid);
            s3 = __builtin_nontemporal_load(srcn + 3 * 1024 + tid);
        }

        // ---- gather current plane ----
        const int b    = plc / CPLANE;
        const int c_in = plc - b * CPLANE;
        const int pw   = c_in % 7;
        const int ph   = (c_in / 7) % 7;
        const int  nb   = ws[b];
        const int* list = ws + NBATCH + b * R;

        for (int base = 0; base < nb; base += 256) {
            const int k = base + (tid >> 2);
            if (k < nb) {
                const int ri = list[k];
                const float* roi = rois + (size_t)ri * 5;   // hot 40 KB, cache-resident
                const float x1 = roi[1] * SSCALE;
                const float y1 = roi[2] * SSCALE;
                const float bw = fmaxf(roi[3] * SSCALE - x1, 0.1f) * (1.0f / 7.0f);
                const float bh = fmaxf(roi[4] * SSCALE - y1, 0.1f) * (1.0f / 7.0f);

                float y = y1 + ((float)ph + sy) * bh;
                y = fminf(fmaxf(y, 0.0f), 127.0f);
                float y0f = floorf(y);
                int   y0  = (int)y0f;
                float ly  = y - y0f;
                if (y0 > 126) { y0 = 126; ly = 1.0f; }   // y==127 -> full weight row 127

                float x = x1 + ((float)pw + sx) * bw;
                x = fminf(fmaxf(x, 0.0f), 127.0f);
                float x0f = floorf(x);
                int   x0  = (int)x0f;
                float lx  = x - x0f;
                if (x0 > 126) { x0 = 126; lx = 1.0f; }

                const float* p = plane + y0 * FW + x0;
                const float v00 = p[0];
                const float v01 = p[1];
                const float v10 = p[FW];
                const float v11 = p[FW + 1];

                const float top = v00 + (v01 - v00) * lx;
                const float bot = v10 + (v11 - v10) * lx;
                float val = top + (bot - top) * ly;

                val += __shfl_xor(val, 1);
                val += __shfl_xor(val, 2);
                if (sub == 0) out[(size_t)ri * CPLANE + c_in] = val * 0.25f;
            }
        }

        if (!more) break;
        __syncthreads();          // all reads of plane done; safe to overwrite
        gcur = gnext;
        plc  = pln;
    }
}

extern "C" void kernel_launch(void* const* d_in, const int* in_sizes, int n_in,
                              void* d_out, int out_size, void* d_ws, size_t ws_size,
                              hipStream_t stream) {
    const float* feat = (const float*)d_in[0];
    const float* rois = (const float*)d_in[1];
    float* out = (float*)d_out;
    int* ws = (int*)d_ws;

    const int R = in_sizes[1] / 5;   // 2048

    bucket_rois<<<1, 1024, 0, stream>>>(rois, R, ws);
    psroi_stream<<<GRIDB, 1024, 0, stream>>>(feat, rois, ws, out, R);
}